// Round 9
// baseline (704.686 us; speedup 1.0000x reference)
//
#include <hip/hip_runtime.h>
#include <hip/hip_bf16.h>

#define SEQ 4096
#define BATCH 2
#define NH 16
#define DH 64
#define DM 1024

typedef float f32x4 __attribute__((ext_vector_type(4)));
typedef __bf16 bf16x8 __attribute__((ext_vector_type(8)));
typedef __bf16 bf16x4 __attribute__((ext_vector_type(4)));

#define MFMA16(a, b, c) __builtin_amdgcn_mfma_f32_16x16x32_bf16((a), (b), (c), 0, 0, 0)

// LDS layout (round 9): stride 64 elems (128B rows), XOR-swizzled 16B slots:
// slot' = slot ^ (row & 7).  Kills the 8-way bank conflict of the stride-72
// layout (lanes with equal (col+g)&7 shared a 4-bank span; 2.1e7 conflicts).
// Swizzle applied on BOTH write and read (reg-staged, rule #21 safe).

// ---------------------------------------------------------------------------
// One-shot fp32 -> bf16 convert for GEMM operands (memory-bound, ~20us).
// ---------------------------------------------------------------------------
__global__ __launch_bounds__(256) void cvt7_kernel(
    const float* __restrict__ a0, const float* __restrict__ a1, const float* __restrict__ a2,
    const float* __restrict__ a3, const float* __restrict__ a4, const float* __restrict__ a5,
    const float* __restrict__ a6,
    __bf16* __restrict__ b0, __bf16* __restrict__ b1, __bf16* __restrict__ b2,
    __bf16* __restrict__ b3, __bf16* __restrict__ b4, __bf16* __restrict__ b5,
    __bf16* __restrict__ b6, int nbig, int nw)
{
    const int y = blockIdx.y;
    const float* s; __bf16* d; int n;
    switch (y) {
        case 0: s = a0; d = b0; n = nbig; break;
        case 1: s = a1; d = b1; n = nbig; break;
        case 2: s = a2; d = b2; n = nbig; break;
        case 3: s = a3; d = b3; n = nw;   break;
        case 4: s = a4; d = b4; n = nw;   break;
        case 5: s = a5; d = b5; n = nw;   break;
        default: s = a6; d = b6; n = nw;  break;
    }
    const int idx = (blockIdx.x * 256 + threadIdx.x) * 8;
    if (idx >= n) return;
    const float4 v0 = *(const float4*)(s + idx);
    const float4 v1 = *(const float4*)(s + idx + 4);
    bf16x8 o;
    o[0] = (__bf16)v0.x; o[1] = (__bf16)v0.y; o[2] = (__bf16)v0.z; o[3] = (__bf16)v0.w;
    o[4] = (__bf16)v1.x; o[5] = (__bf16)v1.y; o[6] = (__bf16)v1.z; o[7] = (__bf16)v1.w;
    *(bf16x8*)(d + idx) = o;
}

// ---------------------------------------------------------------------------
// QKV projection, bf16, swizzled LDS: C = X @ W^T + bias  (NT, 128x128, BK=64)
// z=0 -> q PRE-SCALED by 1/sqrt(64)*log2e; z=1 -> k; z=2 -> v^T (B,H,64,S)
// ---------------------------------------------------------------------------
__global__ __launch_bounds__(256) void qkv_proj_kernel(
    const __bf16* __restrict__ Qb, const __bf16* __restrict__ Kb, const __bf16* __restrict__ Vb,
    const __bf16* __restrict__ Wq, const __bf16* __restrict__ Wk, const __bf16* __restrict__ Wv,
    const float* __restrict__ bq, const float* __restrict__ bk, const float* __restrict__ bv,
    __bf16* __restrict__ qo, __bf16* __restrict__ ko, __bf16* __restrict__ vto)
{
    const int z = blockIdx.z;
    const __bf16* __restrict__ X    = (z == 0) ? Qb : (z == 1) ? Kb : Vb;
    const __bf16* __restrict__ W    = (z == 0) ? Wq : (z == 1) ? Wk : Wv;
    const float*  __restrict__ bias = (z == 0) ? bq : (z == 1) ? bk : bv;

    __shared__ __bf16 la[128 * 64];
    __shared__ __bf16 lb[128 * 64];

    const int t = threadIdx.x;
    const int lane = t & 63;
    const int w = t >> 6;
    const int wr = w >> 1, wc = w & 1;
    const int m0 = blockIdx.y * 128;
    const int n0 = blockIdx.x * 128;
    const int col_l = lane & 15;
    const int row_l = (lane >> 4) * 4;
    const int g = lane >> 4;
    const int swz = col_l & 7;              // read-side swizzle key (row&7)

    const int srow = t >> 1;                // staging: 2 threads/row, 32 bf16 each
    const int sbase = (t & 1) * 4;          // first of 4 slots this thread writes
    const int wkey = srow & 7;              // write-side swizzle key

    f32x4 acc[4][4];
#pragma unroll
    for (int i = 0; i < 4; ++i)
#pragma unroll
        for (int j = 0; j < 4; ++j) acc[i][j] = f32x4{0.f, 0.f, 0.f, 0.f};

    for (int k0 = 0; k0 < DM; k0 += 64) {
        const bf16x8* ap = (const bf16x8*)(X + (size_t)(m0 + srow) * DM + k0 + sbase * 8);
        const bf16x8* bp = (const bf16x8*)(W + (size_t)(n0 + srow) * DM + k0 + sbase * 8);
        bf16x8 av[4], bv4[4];
#pragma unroll
        for (int c = 0; c < 4; ++c) av[c] = ap[c];
#pragma unroll
        for (int c = 0; c < 4; ++c) bv4[c] = bp[c];
        __syncthreads();
#pragma unroll
        for (int c = 0; c < 4; ++c) {
            const int slot = (sbase + c) ^ wkey;
            *(bf16x8*)&la[srow * 64 + slot * 8] = av[c];
            *(bf16x8*)&lb[srow * 64 + slot * 8] = bv4[c];
        }
        __syncthreads();
#pragma unroll
        for (int kk = 0; kk < 2; ++kk) {
            bf16x8 afr[4], bfr[4];
            const int rslot = ((kk * 4 + g) ^ swz) * 8;
#pragma unroll
            for (int i = 0; i < 4; ++i)
                afr[i] = *(const bf16x8*)&la[(wr * 64 + i * 16 + col_l) * 64 + rslot];
#pragma unroll
            for (int j = 0; j < 4; ++j)
                bfr[j] = *(const bf16x8*)&lb[(wc * 64 + j * 16 + col_l) * 64 + rslot];
#pragma unroll
            for (int i = 0; i < 4; ++i)
#pragma unroll
                for (int j = 0; j < 4; ++j)
                    acc[i][j] = MFMA16(afr[i], bfr[j], acc[i][j]);
        }
    }

    const float qscale = (z == 0) ? 0.125f * 1.44269504f : 1.0f;

    // epilogue: C/D layout col=lane&15, row=(lane>>4)*4+reg  [m89]
#pragma unroll
    for (int i = 0; i < 4; ++i) {
#pragma unroll
        for (int j = 0; j < 4; ++j) {
            const int n = n0 + wc * 64 + j * 16 + col_l;
            const float bb = bias[n];
            const int hh = n >> 6, d = n & 63;
            const int mbase = m0 + wr * 64 + i * 16 + row_l;
            const int b = mbase >> 12;
            const int s = mbase & 4095;
            if (z == 2) {
                bf16x4 pk;
#pragma unroll
                for (int r = 0; r < 4; ++r) pk[r] = (__bf16)(acc[i][j][r] + bb);
                *(bf16x4*)&vto[((size_t)((b * NH + hh) * DH + d)) * SEQ + s] = pk;
            } else {
                __bf16* op = (z == 0) ? qo : ko;
#pragma unroll
                for (int r = 0; r < 4; ++r)
                    op[((size_t)((b * NH + hh) * SEQ + s + r)) * DH + d] =
                        (__bf16)((acc[i][j][r] + bb) * qscale);
            }
        }
    }
}

// ---------------------------------------------------------------------------
// Flash attention, round-9: swizzled stride-64 LDS (2-way max), 3 blocks/CU.
// Swapped-operand QK^T + MFMA-ones row-sum + defer-rescale as round-8.
// ---------------------------------------------------------------------------
__global__ __launch_bounds__(256, 3) void attn_kernel(
    const __bf16* __restrict__ qg, const __bf16* __restrict__ kg,
    const __bf16* __restrict__ vtg, const float* __restrict__ maskg,
    __bf16* __restrict__ og)
{
    const int bh = blockIdx.y;
    const int b = bh >> 4;
    const int h = bh & 15;
    const int q0 = blockIdx.x * 256;
    const int t = threadIdx.x;
    const int lane = t & 63;
    const int w = t >> 6;
    const int col_l = lane & 15;
    const int g = lane >> 4;          // 4 lane-groups; key sub-slot g*4+r
    const int swz = col_l & 7;        // read-side swizzle key

    __shared__ __bf16 lk[64 * 64];
    __shared__ __bf16 lv[64 * 64];      // V transposed: row=d, col=key
    __shared__ __bf16 lp[4][64 * 64];   // per-wave P tile: row=q_local, col=key
    __shared__ float lm[64];

    const __bf16* qbase = qg + (size_t)bh * SEQ * DH;
    const __bf16* kbase = kg + (size_t)bh * SEQ * DH;
    const __bf16* vbase = vtg + (size_t)bh * DH * SEQ;

    // Q resident in registers (pre-scaled by 1/sqrt(d)*log2e)
    bf16x8 qf[4][2];
#pragma unroll
    for (int i = 0; i < 4; ++i)
#pragma unroll
        for (int kk = 0; kk < 2; ++kk)
            qf[i][kk] = *(const bf16x8*)&qbase[(size_t)(q0 + w * 64 + i * 16 + col_l) * DH +
                                              kk * 32 + g * 8];

    bf16x8 ones;
#pragma unroll
    for (int e = 0; e < 8; ++e) ones[e] = (__bf16)1.0f;

    f32x4 oaccT[4][4], csum[4];
    float mrun[4];
#pragma unroll
    for (int jd = 0; jd < 4; ++jd)
#pragma unroll
        for (int i = 0; i < 4; ++i) oaccT[jd][i] = f32x4{0.f, 0.f, 0.f, 0.f};
#pragma unroll
    for (int i = 0; i < 4; ++i) { csum[i] = f32x4{0.f, 0.f, 0.f, 0.f}; mrun[i] = -1e30f; }

    const int srow = t >> 2;          // staging: 4 threads/row, 32B each
    const int wkey = srow & 7;
    const int ss0 = ((t & 3) * 2) ^ wkey;        // swizzled slot, first 16B
    const int ss1 = ((t & 3) * 2 + 1) ^ wkey;    // swizzled slot, second 16B

    for (int j0 = 0; j0 < SEQ; j0 += 64) {
        __syncthreads();
        {
            const bf16x8* ksrc = (const bf16x8*)(kbase + (size_t)j0 * DH);  // 8KB contiguous
            bf16x8 k0v = ksrc[t * 2], k1v = ksrc[t * 2 + 1];
            const __bf16* vsrc = vbase + (size_t)srow * SEQ + j0 + (t & 3) * 16;
            bf16x8 v0v = *(const bf16x8*)vsrc;
            bf16x8 v1v = *(const bf16x8*)(vsrc + 8);
            *(bf16x8*)&lk[srow * 64 + ss0 * 8] = k0v;
            *(bf16x8*)&lk[srow * 64 + ss1 * 8] = k1v;
            *(bf16x8*)&lv[srow * 64 + ss0 * 8] = v0v;
            *(bf16x8*)&lv[srow * 64 + ss1 * 8] = v1v;
            if (t < 64) lm[t] = maskg[b * SEQ + j0 + t];
        }
        __syncthreads();

        // mask additive bias (key = j*16 + g*4 + r) -> MFMA C-initializer
        f32x4 msv[4];
#pragma unroll
        for (int j = 0; j < 4; ++j)
#pragma unroll
            for (int r = 0; r < 4; ++r)
                msv[j][r] = (lm[j * 16 + g * 4 + r] == 0.0f) ? -1e9f : 0.0f;

        // K frags hoisted once per tile (A-operand: m=key block j, row=col_l)
        bf16x8 kf[4][2];
#pragma unroll
        for (int j = 0; j < 4; ++j)
#pragma unroll
            for (int kk = 0; kk < 2; ++kk)
                kf[j][kk] = *(const bf16x8*)&lk[(j * 16 + col_l) * 64 +
                                               ((kk * 4 + g) ^ swz) * 8];

        // Per q-block i: S^T = K Q^T (+bias via C-in), per-lane softmax, P->LDS
#pragma unroll
        for (int i = 0; i < 4; ++i) {
            f32x4 sacc[4];
#pragma unroll
            for (int j = 0; j < 4; ++j) sacc[j] = msv[j];
#pragma unroll
            for (int kk = 0; kk < 2; ++kk)
#pragma unroll
                for (int j = 0; j < 4; ++j)
                    sacc[j] = MFMA16(kf[j][kk], qf[i][kk], sacc[j]);
            // sacc[j][r] = S[key = j*16+g*4+r][q = i*16+col_l], log2-domain

            // row max: in-reg + 2 shfl (cross lane-group)
            f32x4 m4 = sacc[0];
            m4 = f32x4{fmaxf(m4[0], sacc[1][0]), fmaxf(m4[1], sacc[1][1]),
                       fmaxf(m4[2], sacc[1][2]), fmaxf(m4[3], sacc[1][3])};
            m4 = f32x4{fmaxf(m4[0], sacc[2][0]), fmaxf(m4[1], sacc[2][1]),
                       fmaxf(m4[2], sacc[2][2]), fmaxf(m4[3], sacc[2][3])};
            m4 = f32x4{fmaxf(m4[0], sacc[3][0]), fmaxf(m4[1], sacc[3][1]),
                       fmaxf(m4[2], sacc[3][2]), fmaxf(m4[3], sacc[3][3])};
            float tmax = fmaxf(fmaxf(m4[0], m4[1]), fmaxf(m4[2], m4[3]));
            tmax = fmaxf(tmax, __shfl_xor(tmax, 16));
            tmax = fmaxf(tmax, __shfl_xor(tmax, 32));

            // defer-rescale: keep old max unless it grew by > THR=8 anywhere
            if (!__all(tmax <= mrun[i] + 8.0f)) {
                const float mnew = fmaxf(mrun[i], tmax);
                const float resc = exp2f(mrun[i] - mnew);
                mrun[i] = mnew;
#pragma unroll
                for (int jd = 0; jd < 4; ++jd) {
                    oaccT[jd][i][0] *= resc; oaccT[jd][i][1] *= resc;
                    oaccT[jd][i][2] *= resc; oaccT[jd][i][3] *= resc;
                }
                csum[i][0] *= resc; csum[i][1] *= resc;
                csum[i][2] *= resc; csum[i][3] *= resc;
            }

#pragma unroll
            for (int j = 0; j < 4; ++j)
#pragma unroll
                for (int r = 0; r < 4; ++r)
                    sacc[j][r] = exp2f(sacc[j][r] - mrun[i]);

            // P pack -> LDS b64: row = q = i*16+col_l; slot (2j+(g>>1))^swz,
            // 8B half g&1  (same involution as reads)
#pragma unroll
            for (int j = 0; j < 4; ++j) {
                bf16x4 pk;
#pragma unroll
                for (int r = 0; r < 4; ++r) pk[r] = (__bf16)sacc[j][r];
                *(bf16x4*)&lp[w][(i * 16 + col_l) * 64 +
                                 ((2 * j + (g >> 1)) ^ swz) * 8 + (g & 1) * 4] = pk;
            }
        }

        // O^T += V^T P^T ; row-sum rides along: csum[i] += ones * P^T
#pragma unroll
        for (int kk = 0; kk < 2; ++kk) {
            bf16x8 vf[4], pf[4];
            const int rslot = ((kk * 4 + g) ^ swz) * 8;
#pragma unroll
            for (int jd = 0; jd < 4; ++jd)
                vf[jd] = *(const bf16x8*)&lv[(jd * 16 + col_l) * 64 + rslot];
#pragma unroll
            for (int i = 0; i < 4; ++i)
                pf[i] = *(const bf16x8*)&lp[w][(i * 16 + col_l) * 64 + rslot];
#pragma unroll
            for (int jd = 0; jd < 4; ++jd)
#pragma unroll
                for (int i = 0; i < 4; ++i)
                    oaccT[jd][i] = MFMA16(vf[jd], pf[i], oaccT[jd][i]);
#pragma unroll
            for (int i = 0; i < 4; ++i)
                csum[i] = MFMA16(ones, pf[i], csum[i]);
        }
    }

    // epilogue: O /= l; lane stores 4 consecutive d (b64) per (i,jd)
#pragma unroll
    for (int i = 0; i < 4; ++i) {
        const float inv = 1.0f / csum[i][0];
        const int s = q0 + w * 64 + i * 16 + col_l;
#pragma unroll
        for (int jd = 0; jd < 4; ++jd) {
            bf16x4 ov;
#pragma unroll
            for (int r = 0; r < 4; ++r) ov[r] = (__bf16)(oaccT[jd][i][r] * inv);
            *(bf16x4*)&og[((size_t)(b * SEQ + s)) * DM + h * DH + jd * 16 + g * 4] = ov;
        }
    }
}

// ---------------------------------------------------------------------------
// Output projection, swizzled LDS: out = A @ Wo^T + bo  (A,W bf16, out fp32)
// ---------------------------------------------------------------------------
__global__ __launch_bounds__(256) void oproj_kernel(
    const __bf16* __restrict__ A, const __bf16* __restrict__ W,
    const float* __restrict__ bias, float* __restrict__ out)
{
    __shared__ __bf16 la[128 * 64];
    __shared__ __bf16 lb[128 * 64];

    const int t = threadIdx.x;
    const int lane = t & 63;
    const int w = t >> 6;
    const int wr = w >> 1, wc = w & 1;
    const int m0 = blockIdx.y * 128;
    const int n0 = blockIdx.x * 128;
    const int col_l = lane & 15;
    const int row_l = (lane >> 4) * 4;
    const int g = lane >> 4;
    const int swz = col_l & 7;

    const int srow = t >> 1;
    const int sbase = (t & 1) * 4;
    const int wkey = srow & 7;

    f32x4 acc[4][4];
#pragma unroll
    for (int i = 0; i < 4; ++i)
#pragma unroll
        for (int j = 0; j < 4; ++j) acc[i][j] = f32x4{0.f, 0.f, 0.f, 0.f};

    for (int k0 = 0; k0 < DM; k0 += 64) {
        const bf16x8* ap = (const bf16x8*)(A + (size_t)(m0 + srow) * DM + k0 + sbase * 8);
        const bf16x8* bp = (const bf16x8*)(W + (size_t)(n0 + srow) * DM + k0 + sbase * 8);
        bf16x8 av[4], bv4[4];
#pragma unroll
        for (int c = 0; c < 4; ++c) av[c] = ap[c];
#pragma unroll
        for (int c = 0; c < 4; ++c) bv4[c] = bp[c];
        __syncthreads();
#pragma unroll
        for (int c = 0; c < 4; ++c) {
            const int slot = (sbase + c) ^ wkey;
            *(bf16x8*)&la[srow * 64 + slot * 8] = av[c];
            *(bf16x8*)&lb[srow * 64 + slot * 8] = bv4[c];
        }
        __syncthreads();
#pragma unroll
        for (int kk = 0; kk < 2; ++kk) {
            bf16x8 afr[4], bfr[4];
            const int rslot = ((kk * 4 + g) ^ swz) * 8;
#pragma unroll
            for (int i = 0; i < 4; ++i)
                afr[i] = *(const bf16x8*)&la[(wr * 64 + i * 16 + col_l) * 64 + rslot];
#pragma unroll
            for (int j = 0; j < 4; ++j)
                bfr[j] = *(const bf16x8*)&lb[(wc * 64 + j * 16 + col_l) * 64 + rslot];
#pragma unroll
            for (int i = 0; i < 4; ++i)
#pragma unroll
                for (int j = 0; j < 4; ++j)
                    acc[i][j] = MFMA16(afr[i], bfr[j], acc[i][j]);
        }
    }

#pragma unroll
    for (int i = 0; i < 4; ++i) {
#pragma unroll
        for (int j = 0; j < 4; ++j) {
            const int n = n0 + wc * 64 + j * 16 + col_l;
            const float bb = bias[n];
            const int mbase = m0 + wr * 64 + i * 16 + row_l;
#pragma unroll
            for (int r = 0; r < 4; ++r)
                out[(size_t)(mbase + r) * DM + n] = acc[i][j][r] + bb;
        }
    }
}

// ---------------------------------------------------------------------------
extern "C" void kernel_launch(void* const* d_in, const int* in_sizes, int n_in,
                              void* d_out, int out_size, void* d_ws, size_t ws_size,
                              hipStream_t stream) {
    (void)in_sizes; (void)n_in; (void)out_size; (void)ws_size;
    const float* Q    = (const float*)d_in[0];
    const float* K    = (const float*)d_in[1];
    const float* V    = (const float*)d_in[2];
    const float* mask = (const float*)d_in[3];
    const float* Wq   = (const float*)d_in[4];
    const float* bq   = (const float*)d_in[5];
    const float* Wk   = (const float*)d_in[6];
    const float* bk   = (const float*)d_in[7];
    const float* Wv   = (const float*)d_in[8];
    const float* bv   = (const float*)d_in[9];
    const float* Wo   = (const float*)d_in[10];
    const float* bo   = (const float*)d_in[11];
    float* out = (float*)d_out;

    const size_t NELEM = (size_t)BATCH * NH * SEQ * DH;  // 8,388,608
    const size_t NW    = (size_t)DM * DM;                // 1,048,576
    __bf16* qb  = (__bf16*)d_ws;       // (B,H,S,64) q, pre-scaled
    __bf16* kb  = qb + NELEM;          // (B,H,S,64)
    __bf16* vtb = kb + NELEM;          // (B,H,64,S)  V pre-transposed
    __bf16* Qb  = vtb + NELEM;         // bf16 inputs
    __bf16* Kb  = Qb + NELEM;
    __bf16* Vb  = Kb + NELEM;
    __bf16* Wqb = Vb + NELEM;          // bf16 weights
    __bf16* Wkb = Wqb + NW;
    __bf16* Wvb = Wkb + NW;
    __bf16* Wob = Wvb + NW;
    __bf16* ab  = Qb;                  // attn out aliases Qb (dead after qkv_proj)

    cvt7_kernel<<<dim3((int)(NELEM / 8 / 256), 7), dim3(256), 0, stream>>>(
        Q, K, V, Wq, Wk, Wv, Wo, Qb, Kb, Vb, Wqb, Wkb, Wvb, Wob,
        (int)NELEM, (int)NW);
    qkv_proj_kernel<<<dim3(8, 64, 3), dim3(256), 0, stream>>>(
        Qb, Kb, Vb, Wqb, Wkb, Wvb, bq, bk, bv, qb, kb, vtb);
    attn_kernel<<<dim3(SEQ / 256, BATCH * NH), dim3(256), 0, stream>>>(
        qb, kb, vtb, mask, ab);
    oproj_kernel<<<dim3(8, 64), dim3(256), 0, stream>>>(ab, Wob, bo, out);
}

// Round 10
// 394.719 us; speedup vs baseline: 1.7853x; 1.7853x over previous
//
#include <hip/hip_runtime.h>
#include <hip/hip_bf16.h>

#define SEQ 4096
#define BATCH 2
#define NH 16
#define DH 64
#define DM 1024

typedef float f32x4 __attribute__((ext_vector_type(4)));
typedef __bf16 bf16x8 __attribute__((ext_vector_type(8)));
typedef __bf16 bf16x4 __attribute__((ext_vector_type(4)));

#define MFMA16(a, b, c) __builtin_amdgcn_mfma_f32_16x16x32_bf16((a), (b), (c), 0, 0, 0)

// LDS layout: stride 64 elems (128B rows), XOR-swizzled 16B slots
// (slot' = slot ^ (row&7)) on BOTH write and read. Round-9 verified:
// conflicts 2.1e7 -> 8.4e6 (b64-write floor). Round-9's (256,3) bound
// caused a VGPR-cap spill (84 regs, +275MB scratch) -> reverted to (256,2).

// ---------------------------------------------------------------------------
// One-shot fp32 -> bf16 convert for GEMM operands (memory-bound, ~20us).
// ---------------------------------------------------------------------------
__global__ __launch_bounds__(256) void cvt7_kernel(
    const float* __restrict__ a0, const float* __restrict__ a1, const float* __restrict__ a2,
    const float* __restrict__ a3, const float* __restrict__ a4, const float* __restrict__ a5,
    const float* __restrict__ a6,
    __bf16* __restrict__ b0, __bf16* __restrict__ b1, __bf16* __restrict__ b2,
    __bf16* __restrict__ b3, __bf16* __restrict__ b4, __bf16* __restrict__ b5,
    __bf16* __restrict__ b6, int nbig, int nw)
{
    const int y = blockIdx.y;
    const float* s; __bf16* d; int n;
    switch (y) {
        case 0: s = a0; d = b0; n = nbig; break;
        case 1: s = a1; d = b1; n = nbig; break;
        case 2: s = a2; d = b2; n = nbig; break;
        case 3: s = a3; d = b3; n = nw;   break;
        case 4: s = a4; d = b4; n = nw;   break;
        case 5: s = a5; d = b5; n = nw;   break;
        default: s = a6; d = b6; n = nw;  break;
    }
    const int idx = (blockIdx.x * 256 + threadIdx.x) * 8;
    if (idx >= n) return;
    const float4 v0 = *(const float4*)(s + idx);
    const float4 v1 = *(const float4*)(s + idx + 4);
    bf16x8 o;
    o[0] = (__bf16)v0.x; o[1] = (__bf16)v0.y; o[2] = (__bf16)v0.z; o[3] = (__bf16)v0.w;
    o[4] = (__bf16)v1.x; o[5] = (__bf16)v1.y; o[6] = (__bf16)v1.z; o[7] = (__bf16)v1.w;
    *(bf16x8*)(d + idx) = o;
}

// ---------------------------------------------------------------------------
// QKV projection, bf16, swizzled LDS: C = X @ W^T + bias  (NT, 128x128, BK=64)
// z=0 -> q PRE-SCALED by 1/sqrt(64)*log2e; z=1 -> k; z=2 -> v^T (B,H,64,S)
// ---------------------------------------------------------------------------
__global__ __launch_bounds__(256) void qkv_proj_kernel(
    const __bf16* __restrict__ Qb, const __bf16* __restrict__ Kb, const __bf16* __restrict__ Vb,
    const __bf16* __restrict__ Wq, const __bf16* __restrict__ Wk, const __bf16* __restrict__ Wv,
    const float* __restrict__ bq, const float* __restrict__ bk, const float* __restrict__ bv,
    __bf16* __restrict__ qo, __bf16* __restrict__ ko, __bf16* __restrict__ vto)
{
    const int z = blockIdx.z;
    const __bf16* __restrict__ X    = (z == 0) ? Qb : (z == 1) ? Kb : Vb;
    const __bf16* __restrict__ W    = (z == 0) ? Wq : (z == 1) ? Wk : Wv;
    const float*  __restrict__ bias = (z == 0) ? bq : (z == 1) ? bk : bv;

    __shared__ __bf16 la[128 * 64];
    __shared__ __bf16 lb[128 * 64];

    const int t = threadIdx.x;
    const int lane = t & 63;
    const int w = t >> 6;
    const int wr = w >> 1, wc = w & 1;
    const int m0 = blockIdx.y * 128;
    const int n0 = blockIdx.x * 128;
    const int col_l = lane & 15;
    const int row_l = (lane >> 4) * 4;
    const int g = lane >> 4;
    const int swz = col_l & 7;              // read-side swizzle key (row&7)

    const int srow = t >> 1;                // staging: 2 threads/row, 32 bf16 each
    const int sbase = (t & 1) * 4;          // first of 4 slots this thread writes
    const int wkey = srow & 7;              // write-side swizzle key

    f32x4 acc[4][4];
#pragma unroll
    for (int i = 0; i < 4; ++i)
#pragma unroll
        for (int j = 0; j < 4; ++j) acc[i][j] = f32x4{0.f, 0.f, 0.f, 0.f};

    for (int k0 = 0; k0 < DM; k0 += 64) {
        const bf16x8* ap = (const bf16x8*)(X + (size_t)(m0 + srow) * DM + k0 + sbase * 8);
        const bf16x8* bp = (const bf16x8*)(W + (size_t)(n0 + srow) * DM + k0 + sbase * 8);
        bf16x8 av[4], bv4[4];
#pragma unroll
        for (int c = 0; c < 4; ++c) av[c] = ap[c];
#pragma unroll
        for (int c = 0; c < 4; ++c) bv4[c] = bp[c];
        __syncthreads();
#pragma unroll
        for (int c = 0; c < 4; ++c) {
            const int slot = (sbase + c) ^ wkey;
            *(bf16x8*)&la[srow * 64 + slot * 8] = av[c];
            *(bf16x8*)&lb[srow * 64 + slot * 8] = bv4[c];
        }
        __syncthreads();
#pragma unroll
        for (int kk = 0; kk < 2; ++kk) {
            bf16x8 afr[4], bfr[4];
            const int rslot = ((kk * 4 + g) ^ swz) * 8;
#pragma unroll
            for (int i = 0; i < 4; ++i)
                afr[i] = *(const bf16x8*)&la[(wr * 64 + i * 16 + col_l) * 64 + rslot];
#pragma unroll
            for (int j = 0; j < 4; ++j)
                bfr[j] = *(const bf16x8*)&lb[(wc * 64 + j * 16 + col_l) * 64 + rslot];
#pragma unroll
            for (int i = 0; i < 4; ++i)
#pragma unroll
                for (int j = 0; j < 4; ++j)
                    acc[i][j] = MFMA16(afr[i], bfr[j], acc[i][j]);
        }
    }

    const float qscale = (z == 0) ? 0.125f * 1.44269504f : 1.0f;

    // epilogue: C/D layout col=lane&15, row=(lane>>4)*4+reg  [m89]
#pragma unroll
    for (int i = 0; i < 4; ++i) {
#pragma unroll
        for (int j = 0; j < 4; ++j) {
            const int n = n0 + wc * 64 + j * 16 + col_l;
            const float bb = bias[n];
            const int hh = n >> 6, d = n & 63;
            const int mbase = m0 + wr * 64 + i * 16 + row_l;
            const int b = mbase >> 12;
            const int s = mbase & 4095;
            if (z == 2) {
                bf16x4 pk;
#pragma unroll
                for (int r = 0; r < 4; ++r) pk[r] = (__bf16)(acc[i][j][r] + bb);
                *(bf16x4*)&vto[((size_t)((b * NH + hh) * DH + d)) * SEQ + s] = pk;
            } else {
                __bf16* op = (z == 0) ? qo : ko;
#pragma unroll
                for (int r = 0; r < 4; ++r)
                    op[((size_t)((b * NH + hh) * SEQ + s + r)) * DH + d] =
                        (__bf16)((acc[i][j][r] + bb) * qscale);
            }
        }
    }
}

// ---------------------------------------------------------------------------
// Flash attention, round-10: swizzled stride-64 LDS, (256,2) bounds (no cap).
// Swapped-operand QK^T + MFMA-ones row-sum + defer-rescale.
// ---------------------------------------------------------------------------
__global__ __launch_bounds__(256, 2) void attn_kernel(
    const __bf16* __restrict__ qg, const __bf16* __restrict__ kg,
    const __bf16* __restrict__ vtg, const float* __restrict__ maskg,
    __bf16* __restrict__ og)
{
    const int bh = blockIdx.y;
    const int b = bh >> 4;
    const int h = bh & 15;
    const int q0 = blockIdx.x * 256;
    const int t = threadIdx.x;
    const int lane = t & 63;
    const int w = t >> 6;
    const int col_l = lane & 15;
    const int g = lane >> 4;          // 4 lane-groups; key sub-slot g*4+r
    const int swz = col_l & 7;        // read-side swizzle key

    __shared__ __bf16 lk[64 * 64];
    __shared__ __bf16 lv[64 * 64];      // V transposed: row=d, col=key
    __shared__ __bf16 lp[4][64 * 64];   // per-wave P tile: row=q_local, col=key
    __shared__ float lm[64];

    const __bf16* qbase = qg + (size_t)bh * SEQ * DH;
    const __bf16* kbase = kg + (size_t)bh * SEQ * DH;
    const __bf16* vbase = vtg + (size_t)bh * DH * SEQ;

    // Q resident in registers (pre-scaled by 1/sqrt(d)*log2e)
    bf16x8 qf[4][2];
#pragma unroll
    for (int i = 0; i < 4; ++i)
#pragma unroll
        for (int kk = 0; kk < 2; ++kk)
            qf[i][kk] = *(const bf16x8*)&qbase[(size_t)(q0 + w * 64 + i * 16 + col_l) * DH +
                                              kk * 32 + g * 8];

    bf16x8 ones;
#pragma unroll
    for (int e = 0; e < 8; ++e) ones[e] = (__bf16)1.0f;

    f32x4 oaccT[4][4], csum[4];
    float mrun[4];
#pragma unroll
    for (int jd = 0; jd < 4; ++jd)
#pragma unroll
        for (int i = 0; i < 4; ++i) oaccT[jd][i] = f32x4{0.f, 0.f, 0.f, 0.f};
#pragma unroll
    for (int i = 0; i < 4; ++i) { csum[i] = f32x4{0.f, 0.f, 0.f, 0.f}; mrun[i] = -1e30f; }

    const int srow = t >> 2;          // staging: 4 threads/row, 32B each
    const int wkey = srow & 7;
    const int ss0 = ((t & 3) * 2) ^ wkey;        // swizzled slot, first 16B
    const int ss1 = ((t & 3) * 2 + 1) ^ wkey;    // swizzled slot, second 16B

    for (int j0 = 0; j0 < SEQ; j0 += 64) {
        __syncthreads();
        {
            const bf16x8* ksrc = (const bf16x8*)(kbase + (size_t)j0 * DH);  // 8KB contiguous
            bf16x8 k0v = ksrc[t * 2], k1v = ksrc[t * 2 + 1];
            const __bf16* vsrc = vbase + (size_t)srow * SEQ + j0 + (t & 3) * 16;
            bf16x8 v0v = *(const bf16x8*)vsrc;
            bf16x8 v1v = *(const bf16x8*)(vsrc + 8);
            *(bf16x8*)&lk[srow * 64 + ss0 * 8] = k0v;
            *(bf16x8*)&lk[srow * 64 + ss1 * 8] = k1v;
            *(bf16x8*)&lv[srow * 64 + ss0 * 8] = v0v;
            *(bf16x8*)&lv[srow * 64 + ss1 * 8] = v1v;
            if (t < 64) lm[t] = maskg[b * SEQ + j0 + t];
        }
        __syncthreads();

        // mask additive bias (key = j*16 + g*4 + r) -> MFMA C-initializer
        f32x4 msv[4];
#pragma unroll
        for (int j = 0; j < 4; ++j)
#pragma unroll
            for (int r = 0; r < 4; ++r)
                msv[j][r] = (lm[j * 16 + g * 4 + r] == 0.0f) ? -1e9f : 0.0f;

        // K frags hoisted once per tile (A-operand: m=key block j, row=col_l)
        bf16x8 kf[4][2];
#pragma unroll
        for (int j = 0; j < 4; ++j)
#pragma unroll
            for (int kk = 0; kk < 2; ++kk)
                kf[j][kk] = *(const bf16x8*)&lk[(j * 16 + col_l) * 64 +
                                               ((kk * 4 + g) ^ swz) * 8];

        // Per q-block i: S^T = K Q^T (+bias via C-in), per-lane softmax, P->LDS
#pragma unroll
        for (int i = 0; i < 4; ++i) {
            f32x4 sacc[4];
#pragma unroll
            for (int j = 0; j < 4; ++j) sacc[j] = msv[j];
#pragma unroll
            for (int kk = 0; kk < 2; ++kk)
#pragma unroll
                for (int j = 0; j < 4; ++j)
                    sacc[j] = MFMA16(kf[j][kk], qf[i][kk], sacc[j]);
            // sacc[j][r] = S[key = j*16+g*4+r][q = i*16+col_l], log2-domain

            // row max: in-reg + 2 shfl (cross lane-group)
            f32x4 m4 = sacc[0];
            m4 = f32x4{fmaxf(m4[0], sacc[1][0]), fmaxf(m4[1], sacc[1][1]),
                       fmaxf(m4[2], sacc[1][2]), fmaxf(m4[3], sacc[1][3])};
            m4 = f32x4{fmaxf(m4[0], sacc[2][0]), fmaxf(m4[1], sacc[2][1]),
                       fmaxf(m4[2], sacc[2][2]), fmaxf(m4[3], sacc[2][3])};
            m4 = f32x4{fmaxf(m4[0], sacc[3][0]), fmaxf(m4[1], sacc[3][1]),
                       fmaxf(m4[2], sacc[3][2]), fmaxf(m4[3], sacc[3][3])};
            float tmax = fmaxf(fmaxf(m4[0], m4[1]), fmaxf(m4[2], m4[3]));
            tmax = fmaxf(tmax, __shfl_xor(tmax, 16));
            tmax = fmaxf(tmax, __shfl_xor(tmax, 32));

            // defer-rescale: keep old max unless it grew by > THR=8 anywhere
            if (!__all(tmax <= mrun[i] + 8.0f)) {
                const float mnew = fmaxf(mrun[i], tmax);
                const float resc = exp2f(mrun[i] - mnew);
                mrun[i] = mnew;
#pragma unroll
                for (int jd = 0; jd < 4; ++jd) {
                    oaccT[jd][i][0] *= resc; oaccT[jd][i][1] *= resc;
                    oaccT[jd][i][2] *= resc; oaccT[jd][i][3] *= resc;
                }
                csum[i][0] *= resc; csum[i][1] *= resc;
                csum[i][2] *= resc; csum[i][3] *= resc;
            }

#pragma unroll
            for (int j = 0; j < 4; ++j)
#pragma unroll
                for (int r = 0; r < 4; ++r)
                    sacc[j][r] = exp2f(sacc[j][r] - mrun[i]);

            // P pack -> LDS b64: row = q = i*16+col_l; slot (2j+(g>>1))^swz,
            // 8B half g&1  (same involution as reads)
#pragma unroll
            for (int j = 0; j < 4; ++j) {
                bf16x4 pk;
#pragma unroll
                for (int r = 0; r < 4; ++r) pk[r] = (__bf16)sacc[j][r];
                *(bf16x4*)&lp[w][(i * 16 + col_l) * 64 +
                                 ((2 * j + (g >> 1)) ^ swz) * 8 + (g & 1) * 4] = pk;
            }
        }

        // O^T += V^T P^T ; row-sum rides along: csum[i] += ones * P^T
#pragma unroll
        for (int kk = 0; kk < 2; ++kk) {
            bf16x8 vf[4], pf[4];
            const int rslot = ((kk * 4 + g) ^ swz) * 8;
#pragma unroll
            for (int jd = 0; jd < 4; ++jd)
                vf[jd] = *(const bf16x8*)&lv[(jd * 16 + col_l) * 64 + rslot];
#pragma unroll
            for (int i = 0; i < 4; ++i)
                pf[i] = *(const bf16x8*)&lp[w][(i * 16 + col_l) * 64 + rslot];
#pragma unroll
            for (int jd = 0; jd < 4; ++jd)
#pragma unroll
                for (int i = 0; i < 4; ++i)
                    oaccT[jd][i] = MFMA16(vf[jd], pf[i], oaccT[jd][i]);
#pragma unroll
            for (int i = 0; i < 4; ++i)
                csum[i] = MFMA16(ones, pf[i], csum[i]);
        }
    }

    // epilogue: O /= l; lane stores 4 consecutive d (b64) per (i,jd)
#pragma unroll
    for (int i = 0; i < 4; ++i) {
        const float inv = 1.0f / csum[i][0];
        const int s = q0 + w * 64 + i * 16 + col_l;
#pragma unroll
        for (int jd = 0; jd < 4; ++jd) {
            bf16x4 ov;
#pragma unroll
            for (int r = 0; r < 4; ++r) ov[r] = (__bf16)(oaccT[jd][i][r] * inv);
            *(bf16x4*)&og[((size_t)(b * SEQ + s)) * DM + h * DH + jd * 16 + g * 4] = ov;
        }
    }
}

// ---------------------------------------------------------------------------
// Output projection, swizzled LDS: out = A @ Wo^T + bo  (A,W bf16, out fp32)
// ---------------------------------------------------------------------------
__global__ __launch_bounds__(256) void oproj_kernel(
    const __bf16* __restrict__ A, const __bf16* __restrict__ W,
    const float* __restrict__ bias, float* __restrict__ out)
{
    __shared__ __bf16 la[128 * 64];
    __shared__ __bf16 lb[128 * 64];

    const int t = threadIdx.x;
    const int lane = t & 63;
    const int w = t >> 6;
    const int wr = w >> 1, wc = w & 1;
    const int m0 = blockIdx.y * 128;
    const int n0 = blockIdx.x * 128;
    const int col_l = lane & 15;
    const int row_l = (lane >> 4) * 4;
    const int g = lane >> 4;
    const int swz = col_l & 7;

    const int srow = t >> 1;
    const int sbase = (t & 1) * 4;
    const int wkey = srow & 7;

    f32x4 acc[4][4];
#pragma unroll
    for (int i = 0; i < 4; ++i)
#pragma unroll
        for (int j = 0; j < 4; ++j) acc[i][j] = f32x4{0.f, 0.f, 0.f, 0.f};

    for (int k0 = 0; k0 < DM; k0 += 64) {
        const bf16x8* ap = (const bf16x8*)(A + (size_t)(m0 + srow) * DM + k0 + sbase * 8);
        const bf16x8* bp = (const bf16x8*)(W + (size_t)(n0 + srow) * DM + k0 + sbase * 8);
        bf16x8 av[4], bv4[4];
#pragma unroll
        for (int c = 0; c < 4; ++c) av[c] = ap[c];
#pragma unroll
        for (int c = 0; c < 4; ++c) bv4[c] = bp[c];
        __syncthreads();
#pragma unroll
        for (int c = 0; c < 4; ++c) {
            const int slot = (sbase + c) ^ wkey;
            *(bf16x8*)&la[srow * 64 + slot * 8] = av[c];
            *(bf16x8*)&lb[srow * 64 + slot * 8] = bv4[c];
        }
        __syncthreads();
#pragma unroll
        for (int kk = 0; kk < 2; ++kk) {
            bf16x8 afr[4], bfr[4];
            const int rslot = ((kk * 4 + g) ^ swz) * 8;
#pragma unroll
            for (int i = 0; i < 4; ++i)
                afr[i] = *(const bf16x8*)&la[(wr * 64 + i * 16 + col_l) * 64 + rslot];
#pragma unroll
            for (int j = 0; j < 4; ++j)
                bfr[j] = *(const bf16x8*)&lb[(wc * 64 + j * 16 + col_l) * 64 + rslot];
#pragma unroll
            for (int i = 0; i < 4; ++i)
#pragma unroll
                for (int j = 0; j < 4; ++j)
                    acc[i][j] = MFMA16(afr[i], bfr[j], acc[i][j]);
        }
    }

#pragma unroll
    for (int i = 0; i < 4; ++i) {
#pragma unroll
        for (int j = 0; j < 4; ++j) {
            const int n = n0 + wc * 64 + j * 16 + col_l;
            const float bb = bias[n];
            const int mbase = m0 + wr * 64 + i * 16 + row_l;
#pragma unroll
            for (int r = 0; r < 4; ++r)
                out[(size_t)(mbase + r) * DM + n] = acc[i][j][r] + bb;
        }
    }
}

// ---------------------------------------------------------------------------
extern "C" void kernel_launch(void* const* d_in, const int* in_sizes, int n_in,
                              void* d_out, int out_size, void* d_ws, size_t ws_size,
                              hipStream_t stream) {
    (void)in_sizes; (void)n_in; (void)out_size; (void)ws_size;
    const float* Q    = (const float*)d_in[0];
    const float* K    = (const float*)d_in[1];
    const float* V    = (const float*)d_in[2];
    const float* mask = (const float*)d_in[3];
    const float* Wq   = (const float*)d_in[4];
    const float* bq   = (const float*)d_in[5];
    const float* Wk   = (const float*)d_in[6];
    const float* bk   = (const float*)d_in[7];
    const float* Wv   = (const float*)d_in[8];
    const float* bv   = (const float*)d_in[9];
    const float* Wo   = (const float*)d_in[10];
    const float* bo   = (const float*)d_in[11];
    float* out = (float*)d_out;

    const size_t NELEM = (size_t)BATCH * NH * SEQ * DH;  // 8,388,608
    const size_t NW    = (size_t)DM * DM;                // 1,048,576
    __bf16* qb  = (__bf16*)d_ws;       // (B,H,S,64) q, pre-scaled
    __bf16* kb  = qb + NELEM;          // (B,H,S,64)
    __bf16* vtb = kb + NELEM;          // (B,H,64,S)  V pre-transposed
    __bf16* Qb  = vtb + NELEM;         // bf16 inputs
    __bf16* Kb  = Qb + NELEM;
    __bf16* Vb  = Kb + NELEM;
    __bf16* Wqb = Vb + NELEM;          // bf16 weights
    __bf16* Wkb = Wqb + NW;
    __bf16* Wvb = Wkb + NW;
    __bf16* Wob = Wvb + NW;
    __bf16* ab  = Qb;                  // attn out aliases Qb (dead after qkv_proj)

    cvt7_kernel<<<dim3((int)(NELEM / 8 / 256), 7), dim3(256), 0, stream>>>(
        Q, K, V, Wq, Wk, Wv, Wo, Qb, Kb, Vb, Wqb, Wkb, Wvb, Wob,
        (int)NELEM, (int)NW);
    qkv_proj_kernel<<<dim3(8, 64, 3), dim3(256), 0, stream>>>(
        Qb, Kb, Vb, Wqb, Wkb, Wvb, bq, bk, bv, qb, kb, vtb);
    attn_kernel<<<dim3(SEQ / 256, BATCH * NH), dim3(256), 0, stream>>>(
        qb, kb, vtb, mask, ab);
    oproj_kernel<<<dim3(8, 64), dim3(256), 0, stream>>>(ab, Wob, bo, out);
}